// Round 5
// baseline (283.638 us; speedup 1.0000x reference)
//
#include <hip/hip_runtime.h>
#include <hip/hip_bf16.h>
#include <stdint.h>

#define B_    4
#define S_    2048
#define DIN   4096
#define DOUT  4096
#define NNZ_  167772
#define M_    (B_*S_)   // 8192

typedef __attribute__((ext_vector_type(4))) float f32x4;
typedef __attribute__((ext_vector_type(8))) short s16x8;
typedef __attribute__((ext_vector_type(8))) unsigned short u16x8;

__device__ __forceinline__ unsigned short f2bf(float f) {
    unsigned int u = __float_as_uint(f);
    u += 0x7FFFu + ((u >> 16) & 1u);   // RNE; inputs finite, no NaN handling needed
    return (unsigned short)(u >> 16);
}

__device__ __forceinline__ float bf2f(unsigned short h) {
    return __uint_as_float(((unsigned int)h) << 16);
}

__device__ __forceinline__ void gload16(const void* g, void* l) {
    __builtin_amdgcn_global_load_lds(
        (const __attribute__((address_space(1))) unsigned int*)g,
        (__attribute__((address_space(3))) unsigned int*)l,
        16, 0, 0);
}

// ---- prep kernels (round-3 verified: no dense delta; bf16 CAS scatter) ----

__global__ void cvt_both_kernel(const float* __restrict__ W,
                                const float* __restrict__ x,
                                unsigned short* __restrict__ Wb,
                                unsigned short* __restrict__ xb,
                                int n8w, int n8x) {
    int i = blockIdx.x * blockDim.x + threadIdx.x;
    const float* src;
    unsigned short* dst;
    int j;
    if (i < n8w) { src = W; dst = Wb; j = i; }
    else         { src = x; dst = xb; j = i - n8w; if (j >= n8x) return; }
    const f32x4* s4 = reinterpret_cast<const f32x4*>(src);
    f32x4 a0 = s4[2*j], a1 = s4[2*j+1];
    u16x8 o;
    o[0]=f2bf(a0[0]); o[1]=f2bf(a0[1]); o[2]=f2bf(a0[2]); o[3]=f2bf(a0[3]);
    o[4]=f2bf(a1[0]); o[5]=f2bf(a1[1]); o[6]=f2bf(a1[2]); o[7]=f2bf(a1[3]);
    reinterpret_cast<u16x8*>(dst)[j] = o;
}

__global__ void scatter_bf16_kernel(const float* __restrict__ vals,
                                    const int* __restrict__ rows,
                                    const int* __restrict__ cols,
                                    unsigned short* __restrict__ Wb, int nnz) {
    int i = blockIdx.x * blockDim.x + threadIdx.x;
    if (i >= nnz) return;
    size_t cell = (size_t)rows[i] * DIN + cols[i];
    unsigned int* word = reinterpret_cast<unsigned int*>(Wb) + (cell >> 1);
    const bool hiHalf = (cell & 1) != 0;
    const float v = vals[i];
    unsigned int old = *word, assumed;
    do {
        assumed = old;
        unsigned short h = hiHalf ? (unsigned short)(assumed >> 16)
                                  : (unsigned short)(assumed & 0xFFFFu);
        unsigned short nh = f2bf(bf2f(h) + v);
        unsigned int nw = hiHalf ? ((assumed & 0x0000FFFFu) | ((unsigned int)nh << 16))
                                 : ((assumed & 0xFFFF0000u) | (unsigned int)nh);
        old = atomicCAS(word, assumed, nw);
    } while (old != assumed);
}

// ---- GEMM: C[m][o] = sum_k xb[m][k] * Wb[o][k] + bias[o] ----
// Round 5: 2 barriers per K-tile. 256x256 tile, BK=64, 8 waves (2Mx4N),
// 512 threads. A TRIPLE-buffered (3x32K), B double-buffered (2x32K) =
// 160 KiB dynamic LDS (full CU pool; 1 block/CU).
//
// Per-tile schedule (A-buf q=t%3, B-buf p=t&1; 2 barriers):
//  H1: BAR; read af1(t)[8, buf q]; stage A(t+2)->Abuf (t+2)%3;
//      MFMA af0*bf0 (16); MFMA af0*bf1 (16); fence vmcnt(4)
//  H2: BAR; read af0(t+1)[8, buf (t+1)%3]; stage B(t+2)->Bbuf p;
//      MFMA af1*bf0 (16); read bf0(t+1)[4, buf 1-p];
//      MFMA af1*bf1 (16); read bf1(t+1)[4, buf 1-p]
//
// Hazard ledger (stage needs readers' lgkm-consumption + 1 barrier):
//  * stage A(t+2)->Abuf (t+2)%3 at t.H1: readers of that buf are tile t-1:
//    af0(t-1) read (t-2).H2 (consumed (t-1).H1, 2 barriers ago); af1(t-1)
//    read (t-1).H1, consumed by (t-1).H2 MFMAs -> lgkm done before wave
//    arrives at t.H1's BAR. SAFE.
//  * stage B(t+2)->Bbuf p at t.H2: readers bf0(t)/bf1(t) both read at
//    (t-1).H2, consumed by t.H1's MFMAs -> lgkm done before t.H2's BAR. SAFE.
//  * fence vmcnt(4) at t.H1 end: outstanding (oldest first) A(t+1)@(t-1).H1,
//    B(t+1)@(t-1).H2, A(t+2)@t.H1 -> keeps newest 4 (A(t+2)) in flight,
//    drains A(t+1)+B(t+1); t.H2's BAR then fences cross-wave before the
//    t+1 reads. Register WAR (bf0/bf1/af0 overwritten after their last
//    consuming MFMA) is enforced by program order within each phase.

__global__ __launch_bounds__(512, 2) void gemm_kernel(
    const unsigned short* __restrict__ A,   // xb [M][K] bf16 bits
    const unsigned short* __restrict__ Bw,  // Wb [N][K] bf16 bits
    const float* __restrict__ bias,
    float* __restrict__ C)                  // [M][N] fp32
{
    constexpr int K  = DIN;    // 4096
    constexpr int N  = DOUT;   // 4096
    constexpr int KB = K * 2;  // 8192 bytes per row
    extern __shared__ char smem[];   // A: 3x32K @0; B: 2x32K @98304; 160 KiB

    const int tid  = threadIdx.x;
    const int wave = tid >> 6;
    const int lane = tid & 63;
    const int wr = wave >> 2;          // 0..1  (M waves)
    const int wc = wave & 3;           // 0..3  (N waves)
    const int l16 = lane & 15;
    const int kq  = lane >> 4;         // 0..3
    const int s7  = l16 & 7;

    // XCD-aware bijective swizzle: 512 wgs, 8 XCDs -> 64 contiguous wgs/XCD.
    const int wg  = blockIdx.x;
    const int swz = (wg & 7) * 64 + (wg >> 3);
    const int bx  = swz & 15;          // N block 0..15
    const int by  = swz >> 4;          // M block 0..31
    const int rowBase = by * 256;
    const int colBase = bx * 256;

    // staging: per-thread global source, pre-swizzled (slot ^= row&7).
    // LDS dest stays linear: base + instr*8192 + wave*1024 (+ lane*16 impl.)
    const int r0    = tid >> 3;                   // row within 64-row chunk
    const int gslot = (tid & 7) ^ (r0 & 7);
    const char* gA = (const char*)A  + (size_t)(rowBase + r0) * KB + gslot * 16;
    const char* gB = (const char*)Bw + (size_t)(colBase + r0) * KB + gslot * 16;
    const int wvoff = wave * 1024;

    // LDS read pointers: row*128B + ((ks*4+kq)^s7)*16B.
    const unsigned q0 = (unsigned)(kq ^ s7);        // ks=0 slot
    const unsigned q1 = (unsigned)((4 + kq) ^ s7);  // ks=1 slot
    const unsigned aBase = (unsigned)((wr * 128 + l16) * 128);
    const unsigned bBase = (unsigned)((wc * 64  + l16) * 128);
    const unsigned short* aPtr[3][2];
    const unsigned short* bPtr[2][2];
    #pragma unroll
    for (int p_ = 0; p_ < 3; ++p_) {
        aPtr[p_][0] = (const unsigned short*)(smem + p_ * 32768 + aBase + q0 * 16);
        aPtr[p_][1] = (const unsigned short*)(smem + p_ * 32768 + aBase + q1 * 16);
    }
    #pragma unroll
    for (int p_ = 0; p_ < 2; ++p_) {
        bPtr[p_][0] = (const unsigned short*)(smem + 98304 + p_ * 32768 + bBase + q0 * 16);
        bPtr[p_][1] = (const unsigned short*)(smem + 98304 + p_ * 32768 + bBase + q1 * 16);
    }

    f32x4 acc[8][4];
    #pragma unroll
    for (int i = 0; i < 8; ++i)
        #pragma unroll
        for (int j = 0; j < 4; ++j) acc[i][j] = f32x4{0.f, 0.f, 0.f, 0.f};

    // persistent fragment registers (live across tiles)
    s16x8 af0[4][2], af1[4][2], bf0[2][2], bf1[2][2];

#define STAGE_A(Q, T, H) do { \
    const char* g_ = gA + (size_t)(T) * 128 + (size_t)(H) * 1048576; \
    gload16(g_,          smem + (Q) * 32768 + (H) * 16384 + wvoff); \
    gload16(g_ + 524288, smem + (Q) * 32768 + (H) * 16384 + 8192 + wvoff); \
} while (0)

#define STAGE_B(P, T, H) do { \
    const char* g_ = gB + (size_t)(T) * 128 + (size_t)(H) * 1048576; \
    gload16(g_,          smem + 98304 + (P) * 32768 + (H) * 16384 + wvoff); \
    gload16(g_ + 524288, smem + 98304 + (P) * 32768 + (H) * 16384 + 8192 + wvoff); \
} while (0)

#define BAR() asm volatile("s_barrier" ::: "memory")

#define MFMA16(D, Af, Bf) D = __builtin_amdgcn_mfma_f32_16x16x32_bf16(Af, Bf, D, 0, 0, 0)

// TILE(QT = A-buf of t, QN = A-buf of t+1, QS = A-buf of t+2, PB = t&1,
//      T = tile index, SS = stage t+2, RN = read t+1 frags, FV = fence:
//      4 -> vmcnt(4), 0 -> vmcnt(0), -1 -> none)
#define TILE(QT, QN, QS, PB, T, SS, RN, FV) do { \
    /* ---- H1 ---- */ \
    BAR(); \
    _Pragma("unroll") \
    for (int m_ = 0; m_ < 4; ++m_) { \
        af1[m_][0] = *(const s16x8*)(aPtr[QT][0] + 4096 + m_ * 1024); \
        af1[m_][1] = *(const s16x8*)(aPtr[QT][1] + 4096 + m_ * 1024); } \
    if (SS) { STAGE_A(QS, (T) + 2, 0); STAGE_A(QS, (T) + 2, 1); } \
    __builtin_amdgcn_s_setprio(1); \
    _Pragma("unroll") \
    for (int m_ = 0; m_ < 4; ++m_) \
      _Pragma("unroll") \
      for (int n_ = 0; n_ < 2; ++n_) { \
        MFMA16(acc[m_][n_], af0[m_][0], bf0[n_][0]); \
        MFMA16(acc[m_][n_], af0[m_][1], bf0[n_][1]); } \
    _Pragma("unroll") \
    for (int m_ = 0; m_ < 4; ++m_) \
      _Pragma("unroll") \
      for (int n_ = 0; n_ < 2; ++n_) { \
        MFMA16(acc[m_][2 + n_], af0[m_][0], bf1[n_][0]); \
        MFMA16(acc[m_][2 + n_], af0[m_][1], bf1[n_][1]); } \
    __builtin_amdgcn_s_setprio(0); \
    if ((FV) == 4)      { asm volatile("s_waitcnt vmcnt(4)" ::: "memory"); } \
    else if ((FV) == 0) { asm volatile("s_waitcnt vmcnt(0)" ::: "memory"); } \
    /* ---- H2 ---- */ \
    BAR(); \
    if (RN) { \
      _Pragma("unroll") \
      for (int m_ = 0; m_ < 4; ++m_) { \
        af0[m_][0] = *(const s16x8*)(aPtr[QN][0] + m_ * 1024); \
        af0[m_][1] = *(const s16x8*)(aPtr[QN][1] + m_ * 1024); } } \
    if (SS) { STAGE_B(PB, (T) + 2, 0); STAGE_B(PB, (T) + 2, 1); } \
    __builtin_amdgcn_s_setprio(1); \
    _Pragma("unroll") \
    for (int m_ = 0; m_ < 4; ++m_) \
      _Pragma("unroll") \
      for (int n_ = 0; n_ < 2; ++n_) { \
        MFMA16(acc[4 + m_][n_], af1[m_][0], bf0[n_][0]); \
        MFMA16(acc[4 + m_][n_], af1[m_][1], bf0[n_][1]); } \
    __builtin_amdgcn_s_setprio(0); \
    if (RN) { \
      _Pragma("unroll") \
      for (int n_ = 0; n_ < 2; ++n_) { \
        bf0[n_][0] = *(const s16x8*)(bPtr[1 - (PB)][0] + n_ * 1024); \
        bf0[n_][1] = *(const s16x8*)(bPtr[1 - (PB)][1] + n_ * 1024); } } \
    __builtin_amdgcn_s_setprio(1); \
    _Pragma("unroll") \
    for (int m_ = 0; m_ < 4; ++m_) \
      _Pragma("unroll") \
      for (int n_ = 0; n_ < 2; ++n_) { \
        MFMA16(acc[4 + m_][2 + n_], af1[m_][0], bf1[n_][0]); \
        MFMA16(acc[4 + m_][2 + n_], af1[m_][1], bf1[n_][1]); } \
    __builtin_amdgcn_s_setprio(0); \
    if (RN) { \
      _Pragma("unroll") \
      for (int n_ = 0; n_ < 2; ++n_) { \
        bf1[n_][0] = *(const s16x8*)(bPtr[1 - (PB)][0] + 2048 + n_ * 1024); \
        bf1[n_][1] = *(const s16x8*)(bPtr[1 - (PB)][1] + 2048 + n_ * 1024); } } \
} while (0)

    // prologue: stage tiles 0,1 (A->bufs 0,1; B->bufs 0,1); wait tile 0
    // landed (keep tile 1's 8 in flight); pre-read af0(0), bf0(0), bf1(0).
    STAGE_A(0, 0, 0); STAGE_A(0, 0, 1);
    STAGE_B(0, 0, 0); STAGE_B(0, 0, 1);
    STAGE_A(1, 1, 0); STAGE_A(1, 1, 1);
    STAGE_B(1, 1, 0); STAGE_B(1, 1, 1);
    asm volatile("s_waitcnt vmcnt(8)" ::: "memory");
    BAR();
    #pragma unroll
    for (int m_ = 0; m_ < 4; ++m_) {
        af0[m_][0] = *(const s16x8*)(aPtr[0][0] + m_ * 1024);
        af0[m_][1] = *(const s16x8*)(aPtr[0][1] + m_ * 1024);
    }
    #pragma unroll
    for (int n_ = 0; n_ < 2; ++n_) {
        bf0[n_][0] = *(const s16x8*)(bPtr[0][0] + n_ * 1024);
        bf0[n_][1] = *(const s16x8*)(bPtr[0][1] + n_ * 1024);
        bf1[n_][0] = *(const s16x8*)(bPtr[0][0] + 2048 + n_ * 1024);
        bf1[n_][1] = *(const s16x8*)(bPtr[0][1] + 2048 + n_ * 1024);
    }

    // main loop: 60 tiles (LCM(2,3)=6 per iteration), then tail 60..63.
    #pragma unroll 1
    for (int t = 0; t < 60; t += 6) {
        TILE(0, 1, 2, 0, t,     1, 1, 4);
        TILE(1, 2, 0, 1, t + 1, 1, 1, 4);
        TILE(2, 0, 1, 0, t + 2, 1, 1, 4);
        TILE(0, 1, 2, 1, t + 3, 1, 1, 4);
        TILE(1, 2, 0, 0, t + 4, 1, 1, 4);
        TILE(2, 0, 1, 1, t + 5, 1, 1, 4);
    }
    TILE(0, 1, 2, 0, 60, 1, 1, 4);
    TILE(1, 2, 0, 1, 61, 1, 1, 4);
    TILE(2, 0, 1, 0, 62, 0, 1, 0);   // no staging; full drain for tile 63
    TILE(0, 1, 2, 1, 63, 0, 0, -1);  // last tile: MFMA only

#undef TILE
#undef MFMA16
#undef BAR
#undef STAGE_A
#undef STAGE_B

    // epilogue: C/D layout col = lane&15, row = (lane>>4)*4 + j
    float bv[4];
    #pragma unroll
    for (int nf = 0; nf < 4; ++nf)
        bv[nf] = bias[colBase + wc * 64 + nf * 16 + l16];

    #pragma unroll
    for (int mf = 0; mf < 8; ++mf) {
        const int rowG = rowBase + wr * 128 + mf * 16 + kq * 4;
        float* cp = C + (size_t)rowG * N + colBase + wc * 64 + l16;
        #pragma unroll
        for (int nf = 0; nf < 4; ++nf)
            #pragma unroll
            for (int j = 0; j < 4; ++j)
                cp[(size_t)j * N + nf * 16] = acc[mf][nf][j] + bv[nf];
    }
}

extern "C" void kernel_launch(void* const* d_in, const int* in_sizes, int n_in,
                              void* d_out, int out_size, void* d_ws, size_t ws_size,
                              hipStream_t stream) {
    const float* x     = (const float*)d_in[0];
    const float* W     = (const float*)d_in[1];
    const float* b     = (const float*)d_in[2];
    const float* dvals = (const float*)d_in[3];
    const int*   drows = (const int*)d_in[4];
    const int*   dcols = (const int*)d_in[5];
    float* out = (float*)d_out;

    char* ws = (char*)d_ws;
    unsigned short* Wb = (unsigned short*)ws;                                   // 32 MiB
    unsigned short* xb = (unsigned short*)(ws + (size_t)32 * 1024 * 1024);      // 64 MiB

    // prep: one merged conversion pass (W->Wb, x->xb), then sparse
    // bf16 CAS-scatter of the corrections into Wb.
    int n8w = DOUT * DIN / 8;  // 2097152
    int n8x = M_ * DIN / 8;    // 4194304
    int nblk = (n8w + n8x) / 256;  // 24576
    cvt_both_kernel<<<nblk, 256, 0, stream>>>(W, x, Wb, xb, n8w, n8x);
    scatter_bf16_kernel<<<(NNZ_ + 255) / 256, 256, 0, stream>>>(dvals, drows, dcols, Wb, NNZ_);

    static bool attr_done = false;
    if (!attr_done) {
        (void)hipFuncSetAttribute(reinterpret_cast<const void*>(gemm_kernel),
                                  hipFuncAttributeMaxDynamicSharedMemorySize, 163840);
        attr_done = true;
    }
    // grid: 512 wgs (16 N-blocks x 32 M-blocks), 512 threads, 160 KiB LDS
    gemm_kernel<<<dim3(512), dim3(512), 163840, stream>>>(xb, Wb, b, out);
}

// Round 6
// 269.446 us; speedup vs baseline: 1.0527x; 1.0527x over previous
//
#include <hip/hip_runtime.h>
#include <hip/hip_bf16.h>
#include <stdint.h>

#define B_    4
#define S_    2048
#define DIN   4096
#define DOUT  4096
#define NNZ_  167772
#define M_    (B_*S_)   // 8192

typedef __attribute__((ext_vector_type(4))) float f32x4;
typedef __attribute__((ext_vector_type(8))) short s16x8;
typedef __attribute__((ext_vector_type(8))) unsigned short u16x8;

__device__ __forceinline__ unsigned short f2bf(float f) {
    unsigned int u = __float_as_uint(f);
    u += 0x7FFFu + ((u >> 16) & 1u);   // RNE; inputs finite, no NaN handling needed
    return (unsigned short)(u >> 16);
}

__device__ __forceinline__ float bf2f(unsigned short h) {
    return __uint_as_float(((unsigned int)h) << 16);
}

__device__ __forceinline__ void gload16(const void* g, void* l) {
    __builtin_amdgcn_global_load_lds(
        (const __attribute__((address_space(1))) unsigned int*)g,
        (__attribute__((address_space(3))) unsigned int*)l,
        16, 0, 0);
}

// ---- prep kernels (round-3 verified: no dense delta; bf16 CAS scatter) ----

__global__ void cvt_both_kernel(const float* __restrict__ W,
                                const float* __restrict__ x,
                                unsigned short* __restrict__ Wb,
                                unsigned short* __restrict__ xb,
                                int n8w, int n8x) {
    int i = blockIdx.x * blockDim.x + threadIdx.x;
    const float* src;
    unsigned short* dst;
    int j;
    if (i < n8w) { src = W; dst = Wb; j = i; }
    else         { src = x; dst = xb; j = i - n8w; if (j >= n8x) return; }
    const f32x4* s4 = reinterpret_cast<const f32x4*>(src);
    f32x4 a0 = s4[2*j], a1 = s4[2*j+1];
    u16x8 o;
    o[0]=f2bf(a0[0]); o[1]=f2bf(a0[1]); o[2]=f2bf(a0[2]); o[3]=f2bf(a0[3]);
    o[4]=f2bf(a1[0]); o[5]=f2bf(a1[1]); o[6]=f2bf(a1[2]); o[7]=f2bf(a1[3]);
    reinterpret_cast<u16x8*>(dst)[j] = o;
}

__global__ void scatter_bf16_kernel(const float* __restrict__ vals,
                                    const int* __restrict__ rows,
                                    const int* __restrict__ cols,
                                    unsigned short* __restrict__ Wb, int nnz) {
    int i = blockIdx.x * blockDim.x + threadIdx.x;
    if (i >= nnz) return;
    size_t cell = (size_t)rows[i] * DIN + cols[i];
    unsigned int* word = reinterpret_cast<unsigned int*>(Wb) + (cell >> 1);
    const bool hiHalf = (cell & 1) != 0;
    const float v = vals[i];
    unsigned int old = *word, assumed;
    do {
        assumed = old;
        unsigned short h = hiHalf ? (unsigned short)(assumed >> 16)
                                  : (unsigned short)(assumed & 0xFFFFu);
        unsigned short nh = f2bf(bf2f(h) + v);
        unsigned int nw = hiHalf ? ((assumed & 0x0000FFFFu) | ((unsigned int)nh << 16))
                                 : ((assumed & 0xFFFF0000u) | (unsigned int)nh);
        old = atomicCAS(word, assumed, nw);
    } while (old != assumed);
}

// ---- GEMM: C[m][o] = sum_k xb[m][k] * Wb[o][k] + bias[o] ----
// Round 6: round-4 structure (4 single-barrier phases, 256x256, BK=64,
// 8 waves 2Mx4N, 128 KiB LDS double-buffered) with (a) 2-phase-lookahead
// ds_reads for EVERY fragment (lgkm waits get >=1 full MFMA phase +
// barrier to resolve) and (b) the S2 fence corrected to vmcnt(0) (round 4
// used vmcnt(4) which left 4 A(t+1) loads in flight while S3 read them —
// a latent race masked by timing).
//
// Per-tile schedule (reads buf p = t&1; 4 barriers):
//   S1: BAR; MFMA af0*bf0 -> acc[0..3][0..1]; read af1(t)      [8]
//   S2: BAR; MFMA af0*bf1 -> acc[0..3][2..3]; vmcnt(0) fence
//   S3: BAR; MFMA af1*bf1 -> acc[4..7][2..3]; read af0(t+1)[8, buf 1-p];
//       stage B(t+2) -> buf p [4]
//   S4: BAR; MFMA af1*bf0 -> acc[4..7][0..1]; read bf0(t+1)+bf1(t+1)
//       [8, buf 1-p]; stage A(t+2) -> buf p [4]
//
// Fragment liveness (all single-buffered in regs, read 2 phases early):
//   af0(t): read (t-1).S3, consumed t.S1/S2    af1(t): read t.S1, cons. t.S3/S4
//   bf0(t): read (t-1).S4, consumed t.S1,S4    bf1(t): read (t-1).S4, cons. t.S2,S3
// Hazard ledger:
//  * fence t.S2: outstanding = B(t+1)[4 @ (t-1).S3] + A(t+1)[4 @ (t-1).S4];
//    vmcnt(0) drains both (issued >=2 phases ago -> no stall); t.S3/S4's
//    t+1 reads are post-fence + post-barrier. t+2 stages issue AFTER the
//    fence, staying in flight across the next tile's S1/S2.
//  * stage B(t+2)->buf p @ t.S3: readers bf0/bf1(t) [read (t-1).S4] are
//    lgkm-consumed before t.S1/S2 MFMA; S3's BAR separates. SAFE.
//  * stage A(t+2)->buf p @ t.S4: readers af0(t) [consumed t.S1], af1(t)
//    [read t.S1, lgkm-consumed before t.S3 MFMA]; S4's BAR separates. SAFE.

__global__ __launch_bounds__(512, 2) void gemm_kernel(
    const unsigned short* __restrict__ A,   // xb [M][K] bf16 bits
    const unsigned short* __restrict__ Bw,  // Wb [N][K] bf16 bits
    const float* __restrict__ bias,
    float* __restrict__ C)                  // [M][N] fp32
{
    constexpr int K  = DIN;    // 4096
    constexpr int N  = DOUT;   // 4096
    constexpr int KB = K * 2;  // 8192 bytes per row
    extern __shared__ char smem[];   // [2 bufs][A 32K | B 32K] = 128 KiB

    const int tid  = threadIdx.x;
    const int wave = tid >> 6;
    const int lane = tid & 63;
    const int wr = wave >> 2;          // 0..1  (M waves)
    const int wc = wave & 3;           // 0..3  (N waves)
    const int l16 = lane & 15;
    const int kq  = lane >> 4;         // 0..3
    const int s7  = l16 & 7;

    // XCD-aware bijective swizzle: 512 wgs, 8 XCDs -> 64 contiguous wgs/XCD.
    const int wg  = blockIdx.x;
    const int swz = (wg & 7) * 64 + (wg >> 3);
    const int bx  = swz & 15;          // N block 0..15
    const int by  = swz >> 4;          // M block 0..31
    const int rowBase = by * 256;
    const int colBase = bx * 256;

    // staging: per-thread global source, pre-swizzled (slot ^= row&7).
    // LDS dest stays linear: base + instr*8192 + wave*1024 (+ lane*16 impl.)
    const int r0    = tid >> 3;                   // row within 64-row chunk
    const int gslot = (tid & 7) ^ (r0 & 7);
    const char* gA = (const char*)A  + (size_t)(rowBase + r0) * KB + gslot * 16;
    const char* gB = (const char*)Bw + (size_t)(colBase + r0) * KB + gslot * 16;
    const int wvoff = wave * 1024;

    // LDS read pointers: row*128B + ((ks*4+kq)^s7)*16B, per buffer.
    const unsigned q0 = (unsigned)(kq ^ s7);        // ks=0 slot
    const unsigned q1 = (unsigned)((4 + kq) ^ s7);  // ks=1 slot
    const unsigned aBase = (unsigned)((wr * 128 + l16) * 128);
    const unsigned bBase = (unsigned)((wc * 64  + l16) * 128);
    const unsigned short* aPtr[2][2];
    const unsigned short* bPtr[2][2];
    #pragma unroll
    for (int p_ = 0; p_ < 2; ++p_) {
        aPtr[p_][0] = (const unsigned short*)(smem + p_ * 65536 + aBase + q0 * 16);
        aPtr[p_][1] = (const unsigned short*)(smem + p_ * 65536 + aBase + q1 * 16);
        bPtr[p_][0] = (const unsigned short*)(smem + p_ * 65536 + 32768 + bBase + q0 * 16);
        bPtr[p_][1] = (const unsigned short*)(smem + p_ * 65536 + 32768 + bBase + q1 * 16);
    }

    f32x4 acc[8][4];
    #pragma unroll
    for (int i = 0; i < 8; ++i)
        #pragma unroll
        for (int j = 0; j < 4; ++j) acc[i][j] = f32x4{0.f, 0.f, 0.f, 0.f};

    // persistent fragment registers (live across tiles)
    s16x8 af0[4][2], af1[4][2], bf0[2][2], bf1[2][2];

#define STAGE_A(P, T, H) do { \
    const char* g_ = gA + (size_t)(T) * 128 + (size_t)(H) * 1048576; \
    gload16(g_,          smem + (P) * 65536 + (H) * 16384 + wvoff); \
    gload16(g_ + 524288, smem + (P) * 65536 + (H) * 16384 + 8192 + wvoff); \
} while (0)

#define STAGE_B(P, T, H) do { \
    const char* g_ = gB + (size_t)(T) * 128 + (size_t)(H) * 1048576; \
    gload16(g_,          smem + (P) * 65536 + 32768 + (H) * 16384 + wvoff); \
    gload16(g_ + 524288, smem + (P) * 65536 + 32768 + (H) * 16384 + 8192 + wvoff); \
} while (0)

#define BAR() asm volatile("s_barrier" ::: "memory")

#define MFMA16(D, Af, Bf) D = __builtin_amdgcn_mfma_f32_16x16x32_bf16(Af, Bf, D, 0, 0, 0)

// TILE(P = buffer parity, T = tile index, SS = stage t+2, RN = read t+1
//      frags, FV = 0 -> vmcnt(0) fence, -1 -> none)
#define TILE(P, T, SS, RN, FV) do { \
    /* ---- S1: af0*bf0; read af1(t) ---- */ \
    BAR(); \
    __builtin_amdgcn_s_setprio(1); \
    _Pragma("unroll") \
    for (int m_ = 0; m_ < 4; ++m_) \
      _Pragma("unroll") \
      for (int n_ = 0; n_ < 2; ++n_) { \
        MFMA16(acc[m_][n_], af0[m_][0], bf0[n_][0]); \
        MFMA16(acc[m_][n_], af0[m_][1], bf0[n_][1]); } \
    __builtin_amdgcn_s_setprio(0); \
    _Pragma("unroll") \
    for (int m_ = 0; m_ < 4; ++m_) { \
        af1[m_][0] = *(const s16x8*)(aPtr[P][0] + 4096 + m_ * 1024); \
        af1[m_][1] = *(const s16x8*)(aPtr[P][1] + 4096 + m_ * 1024); } \
    /* ---- S2: af0*bf1; fence ---- */ \
    BAR(); \
    __builtin_amdgcn_s_setprio(1); \
    _Pragma("unroll") \
    for (int m_ = 0; m_ < 4; ++m_) \
      _Pragma("unroll") \
      for (int n_ = 0; n_ < 2; ++n_) { \
        MFMA16(acc[m_][2 + n_], af0[m_][0], bf1[n_][0]); \
        MFMA16(acc[m_][2 + n_], af0[m_][1], bf1[n_][1]); } \
    __builtin_amdgcn_s_setprio(0); \
    if ((FV) == 0) { asm volatile("s_waitcnt vmcnt(0)" ::: "memory"); } \
    /* ---- S3: af1*bf1; read af0(t+1); stage B(t+2) ---- */ \
    BAR(); \
    __builtin_amdgcn_s_setprio(1); \
    _Pragma("unroll") \
    for (int m_ = 0; m_ < 4; ++m_) \
      _Pragma("unroll") \
      for (int n_ = 0; n_ < 2; ++n_) { \
        MFMA16(acc[4 + m_][2 + n_], af1[m_][0], bf1[n_][0]); \
        MFMA16(acc[4 + m_][2 + n_], af1[m_][1], bf1[n_][1]); } \
    __builtin_amdgcn_s_setprio(0); \
    if (RN) { \
      _Pragma("unroll") \
      for (int m_ = 0; m_ < 4; ++m_) { \
        af0[m_][0] = *(const s16x8*)(aPtr[1 - (P)][0] + m_ * 1024); \
        af0[m_][1] = *(const s16x8*)(aPtr[1 - (P)][1] + m_ * 1024); } } \
    if (SS) { STAGE_B(P, (T) + 2, 0); STAGE_B(P, (T) + 2, 1); } \
    /* ---- S4: af1*bf0; read bf0(t+1)+bf1(t+1); stage A(t+2) ---- */ \
    BAR(); \
    __builtin_amdgcn_s_setprio(1); \
    _Pragma("unroll") \
    for (int m_ = 0; m_ < 4; ++m_) \
      _Pragma("unroll") \
      for (int n_ = 0; n_ < 2; ++n_) { \
        MFMA16(acc[4 + m_][n_], af1[m_][0], bf0[n_][0]); \
        MFMA16(acc[4 + m_][n_], af1[m_][1], bf0[n_][1]); } \
    __builtin_amdgcn_s_setprio(0); \
    if (RN) { \
      _Pragma("unroll") \
      for (int n_ = 0; n_ < 2; ++n_) { \
        bf0[n_][0] = *(const s16x8*)(bPtr[1 - (P)][0] + n_ * 1024); \
        bf0[n_][1] = *(const s16x8*)(bPtr[1 - (P)][1] + n_ * 1024); \
        bf1[n_][0] = *(const s16x8*)(bPtr[1 - (P)][0] + 2048 + n_ * 1024); \
        bf1[n_][1] = *(const s16x8*)(bPtr[1 - (P)][1] + 2048 + n_ * 1024); } } \
    if (SS) { STAGE_A(P, (T) + 2, 0); STAGE_A(P, (T) + 2, 1); } \
} while (0)

    // prologue: stage tiles 0,1; wait tile 0 landed (tile 1's 8 stay in
    // flight); pre-read af0(0), bf0(0), bf1(0) (af1(0) is read in S1).
    STAGE_A(0, 0, 0); STAGE_A(0, 0, 1);
    STAGE_B(0, 0, 0); STAGE_B(0, 0, 1);
    STAGE_B(1, 1, 0); STAGE_B(1, 1, 1);
    STAGE_A(1, 1, 0); STAGE_A(1, 1, 1);
    asm volatile("s_waitcnt vmcnt(8)" ::: "memory");
    BAR();
    #pragma unroll
    for (int m_ = 0; m_ < 4; ++m_) {
        af0[m_][0] = *(const s16x8*)(aPtr[0][0] + m_ * 1024);
        af0[m_][1] = *(const s16x8*)(aPtr[0][1] + m_ * 1024);
    }
    #pragma unroll
    for (int n_ = 0; n_ < 2; ++n_) {
        bf0[n_][0] = *(const s16x8*)(bPtr[0][0] + n_ * 1024);
        bf0[n_][1] = *(const s16x8*)(bPtr[0][1] + n_ * 1024);
        bf1[n_][0] = *(const s16x8*)(bPtr[0][0] + 2048 + n_ * 1024);
        bf1[n_][1] = *(const s16x8*)(bPtr[0][1] + 2048 + n_ * 1024);
    }

    // main loop: tiles 0..61 stage t+2; t=62 reads t+1 only; t=63 drains.
    #pragma unroll 1
    for (int t = 0; t < 62; t += 2) {
        TILE(0, t,     1, 1, 0);
        TILE(1, t + 1, 1, 1, 0);
    }
    TILE(0, 62, 0, 1, 0);
    TILE(1, 63, 0, 0, -1);

#undef TILE
#undef MFMA16
#undef BAR
#undef STAGE_A
#undef STAGE_B

    // epilogue: C/D layout col = lane&15, row = (lane>>4)*4 + j
    float bv[4];
    #pragma unroll
    for (int nf = 0; nf < 4; ++nf)
        bv[nf] = bias[colBase + wc * 64 + nf * 16 + l16];

    #pragma unroll
    for (int mf = 0; mf < 8; ++mf) {
        const int rowG = rowBase + wr * 128 + mf * 16 + kq * 4;
        float* cp = C + (size_t)rowG * N + colBase + wc * 64 + l16;
        #pragma unroll
        for (int nf = 0; nf < 4; ++nf)
            #pragma unroll
            for (int j = 0; j < 4; ++j)
                cp[(size_t)j * N + nf * 16] = acc[mf][nf][j] + bv[nf];
    }
}

extern "C" void kernel_launch(void* const* d_in, const int* in_sizes, int n_in,
                              void* d_out, int out_size, void* d_ws, size_t ws_size,
                              hipStream_t stream) {
    const float* x     = (const float*)d_in[0];
    const float* W     = (const float*)d_in[1];
    const float* b     = (const float*)d_in[2];
    const float* dvals = (const float*)d_in[3];
    const int*   drows = (const int*)d_in[4];
    const int*   dcols = (const int*)d_in[5];
    float* out = (float*)d_out;

    char* ws = (char*)d_ws;
    unsigned short* Wb = (unsigned short*)ws;                                   // 32 MiB
    unsigned short* xb = (unsigned short*)(ws + (size_t)32 * 1024 * 1024);      // 64 MiB

    // prep: one merged conversion pass (W->Wb, x->xb), then sparse
    // bf16 CAS-scatter of the corrections into Wb.
    int n8w = DOUT * DIN / 8;  // 2097152
    int n8x = M_ * DIN / 8;    // 4194304
    int nblk = (n8w + n8x) / 256;  // 24576
    cvt_both_kernel<<<nblk, 256, 0, stream>>>(W, x, Wb, xb, n8w, n8x);
    scatter_bf16_kernel<<<(NNZ_ + 255) / 256, 256, 0, stream>>>(dvals, drows, dcols, Wb, NNZ_);

    static bool attr_done = false;
    if (!attr_done) {
        (void)hipFuncSetAttribute(reinterpret_cast<const void*>(gemm_kernel),
                                  hipFuncAttributeMaxDynamicSharedMemorySize, 131072);
        attr_done = true;
    }
    // grid: 512 wgs (16 N-blocks x 32 M-blocks), 512 threads, 128 KiB LDS
    gemm_kernel<<<dim3(512), dim3(512), 131072, stream>>>(xb, Wb, b, out);
}

// Round 7
// 268.740 us; speedup vs baseline: 1.0554x; 1.0026x over previous
//
#include <hip/hip_runtime.h>
#include <hip/hip_bf16.h>
#include <stdint.h>

#define B_    4
#define S_    2048
#define DIN   4096
#define DOUT  4096
#define NNZ_  167772
#define M_    (B_*S_)   // 8192

typedef __attribute__((ext_vector_type(4))) float f32x4;
typedef __attribute__((ext_vector_type(8))) short s16x8;
typedef __attribute__((ext_vector_type(8))) unsigned short u16x8;

__device__ __forceinline__ unsigned short f2bf(float f) {
    unsigned int u = __float_as_uint(f);
    u += 0x7FFFu + ((u >> 16) & 1u);   // RNE; inputs finite, no NaN handling needed
    return (unsigned short)(u >> 16);
}

__device__ __forceinline__ float bf2f(unsigned short h) {
    return __uint_as_float(((unsigned int)h) << 16);
}

__device__ __forceinline__ void gload16(const void* g, void* l) {
    __builtin_amdgcn_global_load_lds(
        (const __attribute__((address_space(1))) unsigned int*)g,
        (__attribute__((address_space(3))) unsigned int*)l,
        16, 0, 0);
}

// ---- prep kernels (round-3 verified: no dense delta; bf16 CAS scatter) ----

__global__ void cvt_both_kernel(const float* __restrict__ W,
                                const float* __restrict__ x,
                                unsigned short* __restrict__ Wb,
                                unsigned short* __restrict__ xb,
                                int n8w, int n8x) {
    int i = blockIdx.x * blockDim.x + threadIdx.x;
    const float* src;
    unsigned short* dst;
    int j;
    if (i < n8w) { src = W; dst = Wb; j = i; }
    else         { src = x; dst = xb; j = i - n8w; if (j >= n8x) return; }
    const f32x4* s4 = reinterpret_cast<const f32x4*>(src);
    f32x4 a0 = s4[2*j], a1 = s4[2*j+1];
    u16x8 o;
    o[0]=f2bf(a0[0]); o[1]=f2bf(a0[1]); o[2]=f2bf(a0[2]); o[3]=f2bf(a0[3]);
    o[4]=f2bf(a1[0]); o[5]=f2bf(a1[1]); o[6]=f2bf(a1[2]); o[7]=f2bf(a1[3]);
    reinterpret_cast<u16x8*>(dst)[j] = o;
}

__global__ void scatter_bf16_kernel(const float* __restrict__ vals,
                                    const int* __restrict__ rows,
                                    const int* __restrict__ cols,
                                    unsigned short* __restrict__ Wb, int nnz) {
    int i = blockIdx.x * blockDim.x + threadIdx.x;
    if (i >= nnz) return;
    size_t cell = (size_t)rows[i] * DIN + cols[i];
    unsigned int* word = reinterpret_cast<unsigned int*>(Wb) + (cell >> 1);
    const bool hiHalf = (cell & 1) != 0;
    const float v = vals[i];
    unsigned int old = *word, assumed;
    do {
        assumed = old;
        unsigned short h = hiHalf ? (unsigned short)(assumed >> 16)
                                  : (unsigned short)(assumed & 0xFFFFu);
        unsigned short nh = f2bf(bf2f(h) + v);
        unsigned int nw = hiHalf ? ((assumed & 0x0000FFFFu) | ((unsigned int)nh << 16))
                                 : ((assumed & 0xFFFF0000u) | (unsigned int)nh);
        old = atomicCAS(word, assumed, nw);
    } while (old != assumed);
}

// ---- GEMM: C[m][o] = sum_k xb[m][k] * Wb[o][k] + bias[o] ----
// Round 7: two COUNTED vmcnt(4) fences per tile, race-free by schedule
// re-derivation (no drain-to-0 in the loop; no young-load waits).
// 256x256 tile, BK=64, 8 waves (2Mx4N), 512 threads, 128 KiB LDS dbuf.
//
// Phase products: S1 af0*bf0  S2 af1*bf0  S3 af1*bf1  S4 af0*bf1
// (reordered so each fragment's FIRST lgkm-consume precedes any write
//  to its LDS region by >=1 barrier).
//
// Per-tile (reads buf p = t&1; 4 barriers, 2 counted fences):
//  S1: BAR; MFMA af0*bf0
//  S2: BAR; MFMA af1*bf0; vmcnt(4)   [drains A(t+1), issued (t-1).S3 — 3
//                                     phases old; leaves B(t+1) in flight]
//  S3: BAR; MFMA af1*bf1; read af1(t+1)[8, buf 1-p]; stage A(t+2)->buf p;
//      vmcnt(4)                      [drains B(t+1), issued (t-1).S4 — 3
//                                     phases old; leaves A(t+2) in flight]
//  S4: BAR; MFMA af0*bf1; read af0(t+1)[8] + bf0(t+1)[4] + bf1(t+1)[4]
//      (buf 1-p); stage B(t+2)->buf p
//
// Hazard ledger:
//  * read af1(t+1) @ S3: A(t+1) drained by S2-end fence; S3's BAR makes it
//    cross-wave (every wave ran its own fence before any crosses). SAFE.
//  * reads @ S4: A(t+1) drained S2-end; B(t+1) drained S3-end; S4's BAR
//    cross-wave. SAFE.
//  * stage A(t+2)->buf p.A @ S3: region readers af0(t) [read (t-1).S4,
//    lgkm-consumed at t.S1 MFMA head], af1(t) [read (t-1).S3, consumed at
//    t.S2 MFMA head]. Arrival at S3's BAR implies every wave completed S2
//    program order incl. those lgkm waits. SAFE.
//  * stage B(t+2)->buf p.B @ S4: readers bf0(t) [consumed t.S1], bf1(t)
//    [read (t-1).S4, consumed t.S3 MFMA head]; S4's BAR separates. SAFE.
//  * register WAR (within-wave program order): af1 used S2,S3, overwritten
//    S3 after MFMA; af0 used S1,S4, overwritten S4 after MFMA; bf0 used
//    S1,S2, overwritten S4; bf1 used S3,S4, overwritten S4 after MFMA.
//  * fences wait only on loads issued 3 phases (~2000 cyc) earlier ->
//    ~zero stall; staging loads always have a full tile in flight.

__global__ __launch_bounds__(512, 2) void gemm_kernel(
    const unsigned short* __restrict__ A,   // xb [M][K] bf16 bits
    const unsigned short* __restrict__ Bw,  // Wb [N][K] bf16 bits
    const float* __restrict__ bias,
    float* __restrict__ C)                  // [M][N] fp32
{
    constexpr int K  = DIN;    // 4096
    constexpr int N  = DOUT;   // 4096
    constexpr int KB = K * 2;  // 8192 bytes per row
    extern __shared__ char smem[];   // [2 bufs][A 32K | B 32K] = 128 KiB

    const int tid  = threadIdx.x;
    const int wave = tid >> 6;
    const int lane = tid & 63;
    const int wr = wave >> 2;          // 0..1  (M waves)
    const int wc = wave & 3;           // 0..3  (N waves)
    const int l16 = lane & 15;
    const int kq  = lane >> 4;         // 0..3
    const int s7  = l16 & 7;

    // XCD-aware bijective swizzle: 512 wgs, 8 XCDs -> 64 contiguous wgs/XCD.
    const int wg  = blockIdx.x;
    const int swz = (wg & 7) * 64 + (wg >> 3);
    const int bx  = swz & 15;          // N block 0..15
    const int by  = swz >> 4;          // M block 0..31
    const int rowBase = by * 256;
    const int colBase = bx * 256;

    // staging: per-thread global source, pre-swizzled (slot ^= row&7).
    // LDS dest stays linear: base + instr*8192 + wave*1024 (+ lane*16 impl.)
    const int r0    = tid >> 3;                   // row within 64-row chunk
    const int gslot = (tid & 7) ^ (r0 & 7);
    const char* gA = (const char*)A  + (size_t)(rowBase + r0) * KB + gslot * 16;
    const char* gB = (const char*)Bw + (size_t)(colBase + r0) * KB + gslot * 16;
    const int wvoff = wave * 1024;

    // LDS read pointers: row*128B + ((ks*4+kq)^s7)*16B, per buffer.
    const unsigned q0 = (unsigned)(kq ^ s7);        // ks=0 slot
    const unsigned q1 = (unsigned)((4 + kq) ^ s7);  // ks=1 slot
    const unsigned aBase = (unsigned)((wr * 128 + l16) * 128);
    const unsigned bBase = (unsigned)((wc * 64  + l16) * 128);
    const unsigned short* aPtr[2][2];
    const unsigned short* bPtr[2][2];
    #pragma unroll
    for (int p_ = 0; p_ < 2; ++p_) {
        aPtr[p_][0] = (const unsigned short*)(smem + p_ * 65536 + aBase + q0 * 16);
        aPtr[p_][1] = (const unsigned short*)(smem + p_ * 65536 + aBase + q1 * 16);
        bPtr[p_][0] = (const unsigned short*)(smem + p_ * 65536 + 32768 + bBase + q0 * 16);
        bPtr[p_][1] = (const unsigned short*)(smem + p_ * 65536 + 32768 + bBase + q1 * 16);
    }

    f32x4 acc[8][4];
    #pragma unroll
    for (int i = 0; i < 8; ++i)
        #pragma unroll
        for (int j = 0; j < 4; ++j) acc[i][j] = f32x4{0.f, 0.f, 0.f, 0.f};

    // persistent fragment registers (live across tiles)
    s16x8 af0[4][2], af1[4][2], bf0[2][2], bf1[2][2];

#define STAGE_A(P, T, H) do { \
    const char* g_ = gA + (size_t)(T) * 128 + (size_t)(H) * 1048576; \
    gload16(g_,          smem + (P) * 65536 + (H) * 16384 + wvoff); \
    gload16(g_ + 524288, smem + (P) * 65536 + (H) * 16384 + 8192 + wvoff); \
} while (0)

#define STAGE_B(P, T, H) do { \
    const char* g_ = gB + (size_t)(T) * 128 + (size_t)(H) * 1048576; \
    gload16(g_,          smem + (P) * 65536 + 32768 + (H) * 16384 + wvoff); \
    gload16(g_ + 524288, smem + (P) * 65536 + 32768 + (H) * 16384 + 8192 + wvoff); \
} while (0)

#define BAR() asm volatile("s_barrier" ::: "memory")

#define MFMA16(D, Af, Bf) D = __builtin_amdgcn_mfma_f32_16x16x32_bf16(Af, Bf, D, 0, 0, 0)

// TILE(P = buffer parity, T = tile, SS = stage t+2, RN = read t+1 frags,
//      F2 = S2-end fence (4 | -1), F3 = S3-end fence (4 | 0 | -1))
#define TILE(P, T, SS, RN, F2, F3) do { \
    /* ---- S1: af0*bf0 ---- */ \
    BAR(); \
    __builtin_amdgcn_s_setprio(1); \
    _Pragma("unroll") \
    for (int m_ = 0; m_ < 4; ++m_) \
      _Pragma("unroll") \
      for (int n_ = 0; n_ < 2; ++n_) { \
        MFMA16(acc[m_][n_], af0[m_][0], bf0[n_][0]); \
        MFMA16(acc[m_][n_], af0[m_][1], bf0[n_][1]); } \
    __builtin_amdgcn_s_setprio(0); \
    /* ---- S2: af1*bf0; counted fence (drain A(t+1)) ---- */ \
    BAR(); \
    __builtin_amdgcn_s_setprio(1); \
    _Pragma("unroll") \
    for (int m_ = 0; m_ < 4; ++m_) \
      _Pragma("unroll") \
      for (int n_ = 0; n_ < 2; ++n_) { \
        MFMA16(acc[4 + m_][n_], af1[m_][0], bf0[n_][0]); \
        MFMA16(acc[4 + m_][n_], af1[m_][1], bf0[n_][1]); } \
    __builtin_amdgcn_s_setprio(0); \
    if ((F2) == 4) { asm volatile("s_waitcnt vmcnt(4)" ::: "memory"); } \
    /* ---- S3: af1*bf1; read af1(t+1); stage A(t+2); fence (drain B(t+1)) */ \
    BAR(); \
    __builtin_amdgcn_s_setprio(1); \
    _Pragma("unroll") \
    for (int m_ = 0; m_ < 4; ++m_) \
      _Pragma("unroll") \
      for (int n_ = 0; n_ < 2; ++n_) { \
        MFMA16(acc[4 + m_][2 + n_], af1[m_][0], bf1[n_][0]); \
        MFMA16(acc[4 + m_][2 + n_], af1[m_][1], bf1[n_][1]); } \
    __builtin_amdgcn_s_setprio(0); \
    if (RN) { \
      _Pragma("unroll") \
      for (int m_ = 0; m_ < 4; ++m_) { \
        af1[m_][0] = *(const s16x8*)(aPtr[1 - (P)][0] + 4096 + m_ * 1024); \
        af1[m_][1] = *(const s16x8*)(aPtr[1 - (P)][1] + 4096 + m_ * 1024); } } \
    if (SS) { STAGE_A(P, (T) + 2, 0); STAGE_A(P, (T) + 2, 1); } \
    if ((F3) == 4)      { asm volatile("s_waitcnt vmcnt(4)" ::: "memory"); } \
    else if ((F3) == 0) { asm volatile("s_waitcnt vmcnt(0)" ::: "memory"); } \
    /* ---- S4: af0*bf1; read af0/bf0/bf1(t+1); stage B(t+2) ---- */ \
    BAR(); \
    __builtin_amdgcn_s_setprio(1); \
    _Pragma("unroll") \
    for (int m_ = 0; m_ < 4; ++m_) \
      _Pragma("unroll") \
      for (int n_ = 0; n_ < 2; ++n_) { \
        MFMA16(acc[m_][2 + n_], af0[m_][0], bf1[n_][0]); \
        MFMA16(acc[m_][2 + n_], af0[m_][1], bf1[n_][1]); } \
    __builtin_amdgcn_s_setprio(0); \
    if (RN) { \
      _Pragma("unroll") \
      for (int m_ = 0; m_ < 4; ++m_) { \
        af0[m_][0] = *(const s16x8*)(aPtr[1 - (P)][0] + m_ * 1024); \
        af0[m_][1] = *(const s16x8*)(aPtr[1 - (P)][1] + m_ * 1024); } \
      _Pragma("unroll") \
      for (int n_ = 0; n_ < 2; ++n_) { \
        bf0[n_][0] = *(const s16x8*)(bPtr[1 - (P)][0] + n_ * 1024); \
        bf0[n_][1] = *(const s16x8*)(bPtr[1 - (P)][1] + n_ * 1024); \
        bf1[n_][0] = *(const s16x8*)(bPtr[1 - (P)][0] + 2048 + n_ * 1024); \
        bf1[n_][1] = *(const s16x8*)(bPtr[1 - (P)][1] + 2048 + n_ * 1024); } } \
    if (SS) { STAGE_B(P, (T) + 2, 0); STAGE_B(P, (T) + 2, 1); } \
} while (0)

    // prologue: stage tile0 then tile1 (A before B in each, matching the
    // steady-state A-older-than-B queue order); drain tile0 (vmcnt(8)
    // keeps tile1's 8 in flight); pre-read ALL tile-0 fragments.
    STAGE_A(0, 0, 0); STAGE_A(0, 0, 1);
    STAGE_B(0, 0, 0); STAGE_B(0, 0, 1);
    STAGE_A(1, 1, 0); STAGE_A(1, 1, 1);
    STAGE_B(1, 1, 0); STAGE_B(1, 1, 1);
    asm volatile("s_waitcnt vmcnt(8)" ::: "memory");
    BAR();
    #pragma unroll
    for (int m_ = 0; m_ < 4; ++m_) {
        af0[m_][0] = *(const s16x8*)(aPtr[0][0] + m_ * 1024);
        af0[m_][1] = *(const s16x8*)(aPtr[0][1] + m_ * 1024);
        af1[m_][0] = *(const s16x8*)(aPtr[0][0] + 4096 + m_ * 1024);
        af1[m_][1] = *(const s16x8*)(aPtr[0][1] + 4096 + m_ * 1024);
    }
    #pragma unroll
    for (int n_ = 0; n_ < 2; ++n_) {
        bf0[n_][0] = *(const s16x8*)(bPtr[0][0] + n_ * 1024);
        bf0[n_][1] = *(const s16x8*)(bPtr[0][1] + n_ * 1024);
        bf1[n_][0] = *(const s16x8*)(bPtr[0][0] + 2048 + n_ * 1024);
        bf1[n_][1] = *(const s16x8*)(bPtr[0][1] + 2048 + n_ * 1024);
    }

    // main loop: tiles 0..61 full; 62 reads t+1 only (B(63) drains via
    // F3=0 — outstanding is only B(63), 3 phases old); 63 MFMA-only.
    #pragma unroll 1
    for (int t = 0; t < 62; t += 2) {
        TILE(0, t,     1, 1, 4, 4);
        TILE(1, t + 1, 1, 1, 4, 4);
    }
    TILE(0, 62, 0, 1, 4, 0);
    TILE(1, 63, 0, 0, -1, -1);

#undef TILE
#undef MFMA16
#undef BAR
#undef STAGE_A
#undef STAGE_B

    // epilogue: C/D layout col = lane&15, row = (lane>>4)*4 + j
    float bv[4];
    #pragma unroll
    for (int nf = 0; nf < 4; ++nf)
        bv[nf] = bias[colBase + wc * 64 + nf * 16 + l16];

    #pragma unroll
    for (int mf = 0; mf < 8; ++mf) {
        const int rowG = rowBase + wr * 128 + mf * 16 + kq * 4;
        float* cp = C + (size_t)rowG * N + colBase + wc * 64 + l16;
        #pragma unroll
        for (int nf = 0; nf < 4; ++nf)
            #pragma unroll
            for (int j = 0; j < 4; ++j)
                cp[(size_t)j * N + nf * 16] = acc[mf][nf][j] + bv[nf];
    }
}

extern "C" void kernel_launch(void* const* d_in, const int* in_sizes, int n_in,
                              void* d_out, int out_size, void* d_ws, size_t ws_size,
                              hipStream_t stream) {
    const float* x     = (const float*)d_in[0];
    const float* W     = (const float*)d_in[1];
    const float* b     = (const float*)d_in[2];
    const float* dvals = (const float*)d_in[3];
    const int*   drows = (const int*)d_in[4];
    const int*   dcols = (const int*)d_in[5];
    float* out = (float*)d_out;

    char* ws = (char*)d_ws;
    unsigned short* Wb = (unsigned short*)ws;                                   // 32 MiB
    unsigned short* xb = (unsigned short*)(ws + (size_t)32 * 1024 * 1024);      // 64 MiB

    // prep: one merged conversion pass (W->Wb, x->xb), then sparse
    // bf16 CAS-scatter of the corrections into Wb.
    int n8w = DOUT * DIN / 8;  // 2097152
    int n8x = M_ * DIN / 8;    // 4194304
    int nblk = (n8w + n8x) / 256;  // 24576
    cvt_both_kernel<<<nblk, 256, 0, stream>>>(W, x, Wb, xb, n8w, n8x);
    scatter_bf16_kernel<<<(NNZ_ + 255) / 256, 256, 0, stream>>>(dvals, drows, dcols, Wb, NNZ_);

    static bool attr_done = false;
    if (!attr_done) {
        (void)hipFuncSetAttribute(reinterpret_cast<const void*>(gemm_kernel),
                                  hipFuncAttributeMaxDynamicSharedMemorySize, 131072);
        attr_done = true;
    }
    // grid: 512 wgs (16 N-blocks x 32 M-blocks), 512 threads, 128 KiB LDS
    gemm_kernel<<<dim3(512), dim3(512), 131072, stream>>>(xb, Wb, b, out);
}